// Round 1
// baseline (812.006 us; speedup 1.0000x reference)
//
#include <hip/hip_runtime.h>
#include <hip/hip_bf16.h>

// out[b,i,j] = LAM * A[b,i,j] + ETA * h[b,i] * h[b,j]
// B=128, D=1024, fp32. Memory-bound: ~1 GiB total HBM traffic.

#define LAM 0.95f
#define ETA 0.5f
#define D_LOG2 10          // D = 1024
#define DD_LOG2 20         // D*D = 1048576

__global__ __launch_bounds__(256) void fastweight_kernel(
    const float4* __restrict__ A4,
    const float*  __restrict__ h,
    float4* __restrict__ out4)
{
    // One thread per float4 along j. Total float4s = B*D*D/4 = 33,554,432.
    const int idx4 = blockIdx.x * blockDim.x + threadIdx.x;   // < 2^25
    const int elem = idx4 << 2;                               // first scalar element, < 2^27
    const int b    = elem >> DD_LOG2;
    const int rem  = elem & ((1 << DD_LOG2) - 1);
    const int i    = rem >> D_LOG2;
    const int j    = rem & ((1 << D_LOG2) - 1);               // multiple of 4

    const float* hb = h + (b << D_LOG2);
    const float  s  = hb[i] * ETA;                            // wave-uniform-ish broadcast, L1 hit
    const float4 hj = *reinterpret_cast<const float4*>(hb + j);

    float4 a = A4[idx4];
    float4 o;
    o.x = a.x * LAM + s * hj.x;
    o.y = a.y * LAM + s * hj.y;
    o.z = a.z * LAM + s * hj.z;
    o.w = a.w * LAM + s * hj.w;
    out4[idx4] = o;
}

extern "C" void kernel_launch(void* const* d_in, const int* in_sizes, int n_in,
                              void* d_out, int out_size, void* d_ws, size_t ws_size,
                              hipStream_t stream) {
    const float4* A4 = (const float4*)d_in[0];   // A: [B, D, D] fp32
    const float*  h  = (const float*)d_in[1];    // h: [B, D] fp32
    float4* out4     = (float4*)d_out;           // [B, D, D] fp32

    const int total4 = 128 * 1024 * 1024 / 4;    // 33,554,432
    const int block  = 256;
    const int grid   = total4 / block;           // 131,072
    fastweight_kernel<<<grid, block, 0, stream>>>(A4, h, out4);
}